// Round 5
// baseline (1924.951 us; speedup 1.0000x reference)
//
#include <hip/hip_runtime.h>

#define B_ 128
#define T_ 2048
#define H_ 128
#define IN_ 6
#define GRP_ 8                  // steps per inner group
#define NGRP_ (T_ / GRP_)       // 256
#define CHUNK_ 32               // steps per flag chunk
#define NCHUNK_ (T_ / CHUNK_)   // 64
#define FLAG_STRIDE_ 64         // uints between flags (256B)
#define HS_ 144                 // LDS row stride in shorts
#define XGRING_ 3               // xg ring depth (chunks)
#define XGSLOT_ (CHUNK_ * 8192) // floats per ring slot
#define NFLAGS_ 272             // fh 0-127, fx 128-143, fc 144-271

typedef _Float16 f16x8 __attribute__((ext_vector_type(8)));
typedef float    f32x4 __attribute__((ext_vector_type(4)));

__device__ __forceinline__ unsigned short f2h_u(float f) {
  union { _Float16 h; unsigned short u; } v; v.h = (_Float16)f; return v.u;
}
__device__ __forceinline__ unsigned int pack2(float a, float b) {
  return (unsigned int)f2h_u(a) | ((unsigned int)f2h_u(b) << 16);
}
__device__ __forceinline__ float sigf_(float x) {
  return __builtin_amdgcn_rcpf(1.0f + __expf(-x));
}
__device__ __forceinline__ float tanhf_(float x) {
  return 2.0f * __builtin_amdgcn_rcpf(1.0f + __expf(-2.0f * x)) - 1.0f;
}
__device__ __forceinline__ f16x8 load_w8(const float* __restrict__ p) {
  f16x8 r;
#pragma unroll
  for (int i = 0; i < 8; ++i) r[i] = (_Float16)p[i];
  return r;
}

__global__ void init_flags(unsigned int* flags) {
  flags[blockIdx.x * 256 + threadIdx.x] = 0u;  // grid 68 -> 17408 = 272 flags * 64
}

// lgkm-only barrier: h-exchange visibility WITHOUT draining vmcnt.
#define BARRIER_LGKM()                                              \
  do {                                                              \
    asm volatile("s_waitcnt lgkmcnt(0)" ::: "memory");              \
    __builtin_amdgcn_s_barrier();                                   \
    __builtin_amdgcn_sched_barrier(0);                              \
  } while (0)

// vmcnt is PER-WAVE: before any flag publish, ALL waves drain, then barrier.
#define PUBLISH_FENCE()                                             \
  do {                                                              \
    asm volatile("s_waitcnt vmcnt(0)" ::: "memory");                \
    __builtin_amdgcn_s_barrier();                                   \
  } while (0)

// ---------------------------------------------------------------------------
// R17: batch-2 slices, 4-wave (256-thread) WGs, 192 rec WGs + 16 producers.
// Rationale: MFMA work per WG is row-driven (512 gate rows, batch-free), but
// trans-unit (~160cy/SIMD/step at batch-4) and LDS work scale with batch.
// Halving batch per WG and doubling WGs halves trans+LDS per SIMD, halves
// barrier participants (8->4 waves), removes 2-wave lockstep contention.
// Wave w owns row-tiles rt = w+4*jj (jj<8) -> each wave holds ALL 4 gates of
// its h indices; each lane owns ONE h value (h = 16w+64hi+4quad+rsel where
// n16 = rsel*4+hi*2+bcol). Mirror-8 B-cols read one LDS addr (broadcast).
// hstate at HS_=144: 2 rows x 4 quads -> 2-way-max banks, conflict-free.
// Layer 0 stays fused (wx[8] K=8 MFMAs). Producers re-cut to 4 waves, jp<8.
// Flags: fh[l][sl]=l*64+sl (l<2); fx[gl][bg]=128+(gl-1)*8+bg (gl in 1,2);
//        fc[gl][sl]=144+(gl-1)*64+sl.
// ---------------------------------------------------------------------------
__global__ __launch_bounds__(256, 1)
void lstm_pipe(const float* __restrict__ x,
               const float* __restrict__ Wih0, const float* __restrict__ Whh0,
               const float* __restrict__ bih0, const float* __restrict__ bhh0,
               const float* __restrict__ Wih1, const float* __restrict__ Whh1,
               const float* __restrict__ bih1, const float* __restrict__ bhh1,
               const float* __restrict__ Wih2, const float* __restrict__ Whh2,
               const float* __restrict__ bih2, const float* __restrict__ bhh2,
               unsigned short* __restrict__ region,   // f16 [B][T][128]
               float* __restrict__ xg,                // fp32 rings [2][8][3][XGSLOT_]
               unsigned int* __restrict__ state_h,    // [B][128] f16
               unsigned int* __restrict__ flags)
{
  const int bid  = blockIdx.x;
  const int tid  = threadIdx.x;
  const int lane = tid & 63;
  const int wv   = tid >> 6;    // wave 0..3
  const int n16  = lane & 15;
  const int quad = lane >> 4;

  __shared__ unsigned short smem[32 * 16 * HS_];   // 147456 B (producer max)
  __shared__ int s_have;

#define WAITP(ptr_, need_, have_)                                   \
  do {                                                              \
    if ((have_) < (need_)) {                                        \
      if (tid == 0) {                                               \
        int v = (int)__hip_atomic_load(ptr_, __ATOMIC_RELAXED,      \
                                       __HIP_MEMORY_SCOPE_AGENT);   \
        while (v < (need_)) {                                       \
          __builtin_amdgcn_s_sleep(2);                              \
          v = (int)__hip_atomic_load(ptr_, __ATOMIC_RELAXED,        \
                                     __HIP_MEMORY_SCOPE_AGENT);     \
        }                                                           \
        (void)__hip_atomic_load(ptr_, __ATOMIC_ACQUIRE,             \
                                __HIP_MEMORY_SCOPE_AGENT);          \
        s_have = v;                                                 \
      }                                                             \
      __syncthreads();                                              \
      (have_) = s_have;                                             \
    }                                                               \
  } while (0)

  if (bid >= 192) {
    // ======================= GEMM producer role ==========================
    const int gi = bid - 192;
    const int gl = 1 + (gi >> 3);  // produces xg for layer gl (1 or 2)
    const int bg = gi & 7;
    const int b8 = n16 & 7;        // LDS read swizzle key
    const float* Wih = (gl == 1) ? Wih1 : Wih2;
    const float* bih = (gl == 1) ? bih1 : bih2;
    const float* bhh = (gl == 1) ? bhh1 : bhh2;
    float* xgo = xg + (size_t)((gl - 1) * 8 + bg) * (XGRING_ * (size_t)XGSLOT_);
    unsigned int* fx_out = &flags[(128 + (gl - 1) * 8 + bg) * FLAG_STRIDE_];

    f16x8 wih[8][4];
#pragma unroll
    for (int jp = 0; jp < 8; ++jp)
#pragma unroll
      for (int kc = 0; kc < 4; ++kc)
        wih[jp][kc] = load_w8(Wih + (size_t)((wv + 4 * jp) * 16 + n16) * H_ + kc * 32 + quad * 8);
    f32x4 bias4[8];
#pragma unroll
    for (int jp = 0; jp < 8; ++jp)
#pragma unroll
      for (int r = 0; r < 4; ++r) {
        int row = (wv + 4 * jp) * 16 + quad * 4 + r;
        bias4[jp][r] = bih[row] + bhh[row];
      }

    int have_h[8] = {0, 0, 0, 0, 0, 0, 0, 0};
    int have_c[8] = {0, 0, 0, 0, 0, 0, 0, 0};
    for (int k = 0; k < NCHUNK_; ++k) {
#pragma unroll
      for (int q = 0; q < 8; ++q) {
        unsigned int* fp = &flags[((gl - 1) * 64 + 8 * bg + q) * FLAG_STRIDE_];
        WAITP(fp, k + 1, have_h[q]);
      }
      if (k >= XGRING_) {
#pragma unroll
        for (int q = 0; q < 8; ++q) {
          unsigned int* fp = &flags[(144 + (gl - 1) * 64 + 8 * bg + q) * FLAG_STRIDE_];
          WAITP(fp, k - (XGRING_ - 1), have_c[q]);
        }
      }
      // stage h chunk [32 t][16 b][128 h] -> LDS (2 rows per thread), swizzled
#pragma unroll
      for (int rep = 0; rep < 2; ++rep) {
        int row = tid + rep * 256;          // 0..511
        int tt = row >> 4, bb = row & 15;
        int swk = bb & 7;
        const uint4* gp = (const uint4*)(region +
            ((size_t)(bg * 16 + bb) * T_ + (size_t)(CHUNK_ * k + tt)) * H_);
        uint4* lp = (uint4*)&smem[(tt * 16 + bb) * HS_];
#pragma unroll
        for (int i = 0; i < 16; ++i) lp[i ^ swk] = gp[i];
      }
      __syncthreads();
      const int slot = k % XGRING_;
      for (int t = 0; t < CHUNK_; ++t) {
        f16x8 hi4[4];
#pragma unroll
        for (int kc = 0; kc < 4; ++kc)
          hi4[kc] = *(const f16x8*)&smem[(t * 16 + n16) * HS_ +
                                         ((kc * 32 + quad * 8) ^ (b8 << 3))];
        float* xp = xgo + (size_t)(slot * CHUNK_ + t) * 8192 + quad * 64 + n16 * 4;
#pragma unroll
        for (int jp = 0; jp < 8; ++jp) {
          f32x4 a = bias4[jp];
#pragma unroll
          for (int kc = 0; kc < 4; ++kc)
            a = __builtin_amdgcn_mfma_f32_16x16x32_f16(wih[jp][kc], hi4[kc], a, 0, 0, 0);
          *(f32x4*)(xp + (size_t)(wv + 4 * jp) * 256) = a;
        }
      }
      __syncthreads();  // drains stores + protects LDS reuse
      if (tid == 0)
        __hip_atomic_store(fx_out, (unsigned int)(k + 1),
                           __ATOMIC_RELEASE, __HIP_MEMORY_SCOPE_AGENT);
    }
    return;
  }

  // ========================= Recurrence role =============================
  const int layer = bid >> 6;          // 0..2
  const int sl    = bid & 63;          // batch-2 slice
  const int bcol  = n16 & 1;           // batch column (mirror-8)
  const int hib   = (n16 >> 1) & 1;    // acc pair select
  const int rsel  = n16 >> 2;          // acc element select 0..3
  const bool r1   = (rsel & 1) != 0, rr2 = (rsel & 2) != 0;
  const int batch = sl * 2 + bcol;
  const int hcol  = 16 * wv + 64 * hib + 4 * quad + rsel;  // owned h index
  const float* Whh = (layer == 0) ? Whh0 : ((layer == 1) ? Whh1 : Whh2);

  unsigned short* hstate = smem;                 // [2 phase][2 batch][HS_]
  unsigned short* xb = smem + 2 * 2 * HS_;       // [8 s][2 b][8] (layer 0)

  f16x8 whh[8][4];
#pragma unroll
  for (int jj = 0; jj < 8; ++jj)
#pragma unroll
    for (int kc = 0; kc < 4; ++kc)
      whh[jj][kc] = load_w8(Whh + (size_t)((wv + 4 * jj) * 16 + n16) * H_ + kc * 32 + quad * 8);

  for (int i = tid; i < (2 * 2 * HS_) / 2; i += 256) ((unsigned int*)smem)[i] = 0u;

  float cc_ = 0.f;                     // single cell value per lane
  unsigned short dh16[GRP_];
  unsigned int* fh_out = (layer < 2) ? &flags[(layer * 64 + sl) * FLAG_STRIDE_] : nullptr;

  if (layer == 0) {
    // ------------------------- layer 0 (fused x) ------------------------
    f32x4 bias4[8];
#pragma unroll
    for (int jj = 0; jj < 8; ++jj)
#pragma unroll
      for (int r = 0; r < 4; ++r) {
        int row = (wv + 4 * jj) * 16 + quad * 4 + r;
        bias4[jj][r] = bih0[row] + bhh0[row];
      }
    f16x8 wx[8];
#pragma unroll
    for (int jj = 0; jj < 8; ++jj)
#pragma unroll
      for (int i = 0; i < 8; ++i) wx[jj][i] = (_Float16)0.f;
    if (quad == 0) {
#pragma unroll
      for (int jj = 0; jj < 8; ++jj) {
        const float* p = Wih0 + (size_t)((wv + 4 * jj) * 16 + n16) * IN_;
#pragma unroll
        for (int i = 0; i < IN_; ++i) wx[jj][i] = (_Float16)p[i];
      }
    }
    const int sn_x = tid & 1, st_x = tid >> 1;  // staging map (tid<16)
    float xraw[6];
    __syncthreads();   // zeros visible
    if (tid < 16) {
      const float* xp = x + ((size_t)(sl * 2 + sn_x) * T_ + st_x) * IN_;
#pragma unroll
      for (int i = 0; i < IN_; ++i) xraw[i] = xp[i];
      uint4 xr4;
      xr4.x = pack2(xraw[0], xraw[1]); xr4.y = pack2(xraw[2], xraw[3]);
      xr4.z = pack2(xraw[4], xraw[5]); xr4.w = 0u;
      *(uint4*)&xb[(st_x * 2 + sn_x) * 8] = xr4;
    }
    __syncthreads();

    for (int g = 0; g < NGRP_; ++g) {
      if (tid < 16 && g + 1 < NGRP_) {
        const float* xp = x + ((size_t)(sl * 2 + sn_x) * T_ + (8 * (g + 1) + st_x)) * IN_;
#pragma unroll
        for (int i = 0; i < IN_; ++i) xraw[i] = xp[i];
      }
#pragma unroll
      for (int s = 0; s < GRP_; ++s) {
        const int rp = s & 1, wp = rp ^ 1;
        f16x8 hs[4];
#pragma unroll
        for (int kc = 0; kc < 4; ++kc)
          hs[kc] = *(const f16x8*)&hstate[(rp * 2 + bcol) * HS_ + kc * 32 + quad * 8];
        f16x8 xi;
#pragma unroll
        for (int i = 0; i < 8; ++i) xi[i] = (_Float16)0.f;
        if (quad == 0) xi = *(const f16x8*)&xb[(s * 2 + bcol) * 8];
        f32x4 acc[8];
#pragma unroll
        for (int jj = 0; jj < 8; ++jj)
          acc[jj] = __builtin_amdgcn_mfma_f32_16x16x32_f16(wx[jj], xi, bias4[jj], 0, 0, 0);
#pragma unroll
        for (int kc = 0; kc < 4; ++kc)
#pragma unroll
          for (int jj = 0; jj < 8; ++jj)
            acc[jj] = __builtin_amdgcn_mfma_f32_16x16x32_f16(whh[jj][kc], hs[kc], acc[jj], 0, 0, 0);
        float g4[4];
#pragma unroll
        for (int j = 0; j < 4; ++j) {
          f32x4 va;
#pragma unroll
          for (int r = 0; r < 4; ++r) va[r] = hib ? acc[2 * j + 1][r] : acc[2 * j][r];
          float t0 = r1 ? va[1] : va[0];
          float t1 = r1 ? va[3] : va[2];
          g4[j] = rr2 ? t1 : t0;
        }
        float i_ = sigf_(g4[0]), f_ = sigf_(g4[1]), t_ = tanhf_(g4[2]), o_ = sigf_(g4[3]);
        cc_ = f_ * cc_ + i_ * t_;
        float h_ = o_ * tanhf_(cc_);
        unsigned short uh = f2h_u(h_);
        dh16[s] = uh;
        hstate[(wp * 2 + bcol) * HS_ + hcol] = uh;
        BARRIER_LGKM();
      }
      // deferred h stores (in flight until chunk publish) + xb staging
#pragma unroll
      for (int s = 0; s < GRP_; ++s)
        region[((size_t)batch * T_ + (8 * g + s)) * H_ + hcol] = dh16[s];
      if (tid < 16 && g + 1 < NGRP_) {
        uint4 xr4;
        xr4.x = pack2(xraw[0], xraw[1]); xr4.y = pack2(xraw[2], xraw[3]);
        xr4.z = pack2(xraw[4], xraw[5]); xr4.w = 0u;
        *(uint4*)&xb[(st_x * 2 + sn_x) * 8] = xr4;
      }
      BARRIER_LGKM();  // publishes xb; region stores stay in flight
      if ((g & 3) == 3) {
        PUBLISH_FENCE();
        if (tid == 0)
          __hip_atomic_store(fh_out, (unsigned int)((g >> 2) + 1),
                             __ATOMIC_RELEASE, __HIP_MEMORY_SCOPE_AGENT);
      }
    }
  } else {
    // ----------------------- layers 1 and 2 ----------------------------
    const int bg = sl >> 3;
    const float* xgi = xg + (size_t)((layer - 1) * 8 + bg) * (XGRING_ * (size_t)XGSLOT_);
    const int xcol = (sl & 7) * 2 + bcol;   // batch column in the 16-wide tile
    f32x4 xr[2][8];
    auto load_xg = [&](int t, int buf) {
      int slot = (t >> 5) % XGRING_;
      const float* p = xgi + (size_t)(slot * CHUNK_ + (t & 31)) * 8192
                       + quad * 64 + xcol * 4;
#pragma unroll
      for (int jj = 0; jj < 8; ++jj)
        xr[buf][jj] = *(const f32x4*)(p + (size_t)(wv + 4 * jj) * 256);
    };
    unsigned int* fx_in  = &flags[(128 + (layer - 1) * 8 + bg) * FLAG_STRIDE_];
    unsigned int* fc_out = &flags[(144 + (layer - 1) * 64 + sl) * FLAG_STRIDE_];
    int have_x = 0;
    __syncthreads();  // hstate zeros visible

    for (int g = 0; g < NGRP_; ++g) {
      if ((g & 3) == 0) {
        int c = g >> 2;
        WAITP(fx_in, c + 1, have_x);
        load_xg(32 * c, 0);
        load_xg(32 * c + 1, 1);
      }
#pragma unroll
      for (int s = 0; s < GRP_; ++s) {
        const int t = 8 * g + s;
        const int rp = s & 1, wp = rp ^ 1;
        f16x8 hs[4];
#pragma unroll
        for (int kc = 0; kc < 4; ++kc)
          hs[kc] = *(const f16x8*)&hstate[(rp * 2 + bcol) * HS_ + kc * 32 + quad * 8];
        f32x4 acc[8];
#pragma unroll
        for (int jj = 0; jj < 8; ++jj)
          acc[jj] = __builtin_amdgcn_mfma_f32_16x16x32_f16(whh[jj][0], hs[0], xr[s & 1][jj], 0, 0, 0);
        if (!(((g & 3) == 3) && s >= 6)) load_xg(t + 2, s & 1);
#pragma unroll
        for (int kc = 1; kc < 4; ++kc)
#pragma unroll
          for (int jj = 0; jj < 8; ++jj)
            acc[jj] = __builtin_amdgcn_mfma_f32_16x16x32_f16(whh[jj][kc], hs[kc], acc[jj], 0, 0, 0);
        float g4[4];
#pragma unroll
        for (int j = 0; j < 4; ++j) {
          f32x4 va;
#pragma unroll
          for (int r = 0; r < 4; ++r) va[r] = hib ? acc[2 * j + 1][r] : acc[2 * j][r];
          float t0 = r1 ? va[1] : va[0];
          float t1 = r1 ? va[3] : va[2];
          g4[j] = rr2 ? t1 : t0;
        }
        float i_ = sigf_(g4[0]), f_ = sigf_(g4[1]), t_ = tanhf_(g4[2]), o_ = sigf_(g4[3]);
        cc_ = f_ * cc_ + i_ * t_;
        float h_ = o_ * tanhf_(cc_);
        unsigned short uh = f2h_u(h_);
        dh16[s] = uh;
        hstate[(wp * 2 + bcol) * HS_ + hcol] = uh;
        BARRIER_LGKM();
      }
      if (layer == 1) {
#pragma unroll
        for (int s = 0; s < GRP_; ++s)
          region[((size_t)batch * T_ + (8 * g + s)) * H_ + hcol] = dh16[s];
      }
      if ((g & 3) == 3) {
        PUBLISH_FENCE();  // drains region stores + this chunk's xg loads
        if (tid == 0) {
          unsigned int cdone = (unsigned int)((g >> 2) + 1);
          if (layer == 1)
            __hip_atomic_store(fh_out, cdone, __ATOMIC_RELEASE, __HIP_MEMORY_SCOPE_AGENT);
          __hip_atomic_store(fc_out, cdone, __ATOMIC_RELEASE, __HIP_MEMORY_SCOPE_AGENT);
        }
      }
    }
    if (layer == 2)
      ((unsigned short*)state_h)[(size_t)batch * 128 + hcol] = dh16[GRP_ - 1];
  }
#undef WAITP
}

// ---------------------------------------------------------------------------
__global__ void head_kernel(const unsigned int* __restrict__ state_h,
                            const float* __restrict__ Wout,
                            const float* __restrict__ bout,
                            float* __restrict__ out)
{
  int b = threadIdx.x;  // 128 threads, 1 block
  float s = bout[0];
  for (int j = 0; j < 64; ++j) {
    unsigned int p = state_h[b * 64 + j];
    union { unsigned short u; _Float16 h; } lo, hi;
    lo.u = (unsigned short)(p & 0xffffu);
    hi.u = (unsigned short)(p >> 16);
    s += (float)lo.h * Wout[2 * j] + (float)hi.h * Wout[2 * j + 1];
  }
  out[b] = s;
}

// ---------------------------------------------------------------------------
extern "C" void kernel_launch(void* const* d_in, const int* in_sizes, int n_in,
                              void* d_out, int out_size, void* d_ws, size_t ws_size,
                              hipStream_t stream)
{
  const float* x = (const float*)d_in[0];
  const float* Wih[3] = {(const float*)d_in[1], (const float*)d_in[5], (const float*)d_in[9]};
  const float* Whh[3] = {(const float*)d_in[2], (const float*)d_in[6], (const float*)d_in[10]};
  const float* bih[3] = {(const float*)d_in[3], (const float*)d_in[7], (const float*)d_in[11]};
  const float* bhh[3] = {(const float*)d_in[4], (const float*)d_in[8], (const float*)d_in[12]};
  const float* Wout = (const float*)d_in[13];
  const float* bout = (const float*)d_in[14];
  float* out = (float*)d_out;

  char* ws = (char*)d_ws;
  size_t off = 0;
  unsigned short* region = (unsigned short*)(ws + off); off += (size_t)B_ * T_ * H_ * 2;   // 64 MiB
  float* xg = (float*)(ws + off);                       off += (size_t)16 * XGRING_ * XGSLOT_ * 4;  // 48 MiB
  unsigned int* state_h  = (unsigned int*)(ws + off);   off += (size_t)B_ * 64 * 4;
  off = (off + 255) & ~(size_t)255;
  unsigned int* flags    = (unsigned int*)(ws + off);   off += NFLAGS_ * FLAG_STRIDE_ * 4;

  init_flags<<<68, 256, 0, stream>>>(flags);
  lstm_pipe<<<208, 256, 0, stream>>>(x,
      Wih[0], Whh[0], bih[0], bhh[0],
      Wih[1], Whh[1], bih[1], bhh[1],
      Wih[2], Whh[2], bih[2], bhh[2],
      region, xg, state_h, flags);
  head_kernel<<<1, 128, 0, stream>>>(state_h, Wout, bout, out);
}

// Round 6
// 1541.794 us; speedup vs baseline: 1.2485x; 1.2485x over previous
//
#include <hip/hip_runtime.h>

#define B_ 128
#define T_ 2048
#define H_ 128
#define IN_ 6
#define GRP_ 8                  // steps per inner group
#define NGRP_ (T_ / GRP_)       // 256
#define CHUNK_ 32               // steps per flag chunk
#define NCHUNK_ (T_ / CHUNK_)   // 64
#define FLAG_STRIDE_ 64         // uints between flags (256B)
#define HS_ 144                 // LDS row stride in shorts
#define XGRING_ 3               // xg ring depth (chunks)
#define XGSLOT_ (CHUNK_ * 8192) // floats per ring slot
#define NFLAGS_ 272             // fh 0-127, fx 128-143, fc 144-271

typedef _Float16 f16x8 __attribute__((ext_vector_type(8)));
typedef float    f32x4 __attribute__((ext_vector_type(4)));

__device__ __forceinline__ unsigned short f2h_u(float f) {
  union { _Float16 h; unsigned short u; } v; v.h = (_Float16)f; return v.u;
}
__device__ __forceinline__ unsigned int pack2(float a, float b) {
  return (unsigned int)f2h_u(a) | ((unsigned int)f2h_u(b) << 16);
}
__device__ __forceinline__ float sigf_(float x) {
  return __builtin_amdgcn_rcpf(1.0f + __expf(-x));
}
__device__ __forceinline__ float tanhf_(float x) {
  return 2.0f * __builtin_amdgcn_rcpf(1.0f + __expf(-2.0f * x)) - 1.0f;
}
__device__ __forceinline__ f16x8 load_w8(const float* __restrict__ p) {
  f16x8 r;
#pragma unroll
  for (int i = 0; i < 8; ++i) r[i] = (_Float16)p[i];
  return r;
}

__global__ void init_flags(unsigned int* flags) {
  flags[blockIdx.x * 256 + threadIdx.x] = 0u;  // grid 68 -> 17408 = 272 flags * 64
}

// lgkm-only barrier: h-exchange visibility WITHOUT draining vmcnt.
#define BARRIER_LGKM()                                              \
  do {                                                              \
    asm volatile("s_waitcnt lgkmcnt(0)" ::: "memory");              \
    __builtin_amdgcn_s_barrier();                                   \
    __builtin_amdgcn_sched_barrier(0);                              \
  } while (0)

// vmcnt is PER-WAVE: before any flag publish, ALL waves drain, then barrier.
#define PUBLISH_FENCE()                                             \
  do {                                                              \
    asm volatile("s_waitcnt vmcnt(0)" ::: "memory");                \
    __builtin_amdgcn_s_barrier();                                   \
  } while (0)

#define MFMA16(A, B, C) __builtin_amdgcn_mfma_f32_16x16x32_f16((A), (B), (C), 0, 0, 0)

// ---------------------------------------------------------------------------
// R18 = R16 (batch-4 mirror-4, 8-wave rec WGs, vmcnt-free step barriers,
// fenced publishes; 1540us) + surgical scheduling edits:
//  (a) gate chains split into pairs: acc{i,f} (8 MFMA) -> select+exp for i,f
//      (trans pipe) -> acc{g,o} (8 MFMA) -> rest of act. Lets the scheduler
//      hide ~half the trans issue + act latency under MFMA issue (the two
//      lockstep waves otherwise serialize phases: MFMA 620cy then act 160cy).
//  (b) xg slot base hoisted to once per chunk (kills %3 + 64-bit addr build
//      per step), per-step offset is (t&31)*8192.
//  (c) no ci[] copies; xr consumed directly, next-step load issued after.
// Structure/flags/sync identical to R16.
// ---------------------------------------------------------------------------
__global__ __launch_bounds__(512, 2)
void lstm_pipe(const float* __restrict__ x,
               const float* __restrict__ Wih0, const float* __restrict__ Whh0,
               const float* __restrict__ bih0, const float* __restrict__ bhh0,
               const float* __restrict__ Wih1, const float* __restrict__ Whh1,
               const float* __restrict__ bih1, const float* __restrict__ bhh1,
               const float* __restrict__ Wih2, const float* __restrict__ Whh2,
               const float* __restrict__ bih2, const float* __restrict__ bhh2,
               unsigned short* __restrict__ region,   // f16 [B][T][128]
               float* __restrict__ xg,                // fp32 rings [2][8][3][XGSLOT_]
               unsigned int* __restrict__ state_h,    // [B][128] f16
               unsigned int* __restrict__ flags)
{
  const int bid  = blockIdx.x;
  const int tid  = threadIdx.x;
  const int lane = tid & 63;
  const int wv   = tid >> 6;    // wave 0..7
  const int n16  = lane & 15;
  const int quad = lane >> 4;

  __shared__ unsigned short smem[32 * 16 * HS_];   // 147456 B (producer max)
  __shared__ int s_have;

#define WAITP(ptr_, need_, have_)                                   \
  do {                                                              \
    if ((have_) < (need_)) {                                        \
      if (tid == 0) {                                               \
        int v = (int)__hip_atomic_load(ptr_, __ATOMIC_RELAXED,      \
                                       __HIP_MEMORY_SCOPE_AGENT);   \
        while (v < (need_)) {                                       \
          __builtin_amdgcn_s_sleep(2);                              \
          v = (int)__hip_atomic_load(ptr_, __ATOMIC_RELAXED,        \
                                     __HIP_MEMORY_SCOPE_AGENT);     \
        }                                                           \
        (void)__hip_atomic_load(ptr_, __ATOMIC_ACQUIRE,             \
                                __HIP_MEMORY_SCOPE_AGENT);          \
        s_have = v;                                                 \
      }                                                             \
      __syncthreads();                                              \
      (have_) = s_have;                                             \
    }                                                               \
  } while (0)

  if (bid >= 96) {
    // ======================= GEMM producer role ==========================
    const int gi = bid - 96;
    const int gl = 1 + (gi >> 3);  // produces xg for layer gl
    const int bg = gi & 7;
    const int b8 = n16 & 7;        // LDS read swizzle key
    const float* Wih = (gl == 1) ? Wih1 : Wih2;
    const float* bih = (gl == 1) ? bih1 : bih2;
    const float* bhh = (gl == 1) ? bhh1 : bhh2;
    float* xgo = xg + (size_t)((gl - 1) * 8 + bg) * (XGRING_ * (size_t)XGSLOT_);
    unsigned int* fhp[4]; unsigned int* fcp[4];
#pragma unroll
    for (int q = 0; q < 4; ++q) {
      fhp[q] = &flags[((gl - 1) * 32 + 4 * bg + q) * FLAG_STRIDE_];
      fcp[q] = &flags[(144 + (gl - 1) * 64 + 4 * bg + q) * FLAG_STRIDE_];
    }
    unsigned int* fx_out = &flags[(128 + (gl - 1) * 8 + bg) * FLAG_STRIDE_];

    f16x8 wih[4][4];
#pragma unroll
    for (int j = 0; j < 4; ++j)
#pragma unroll
      for (int kc = 0; kc < 4; ++kc)
        wih[j][kc] = load_w8(Wih + (size_t)(j * 128 + 16 * wv + n16) * H_ + kc * 32 + quad * 8);
    f32x4 bias4[4];
#pragma unroll
    for (int j = 0; j < 4; ++j)
#pragma unroll
      for (int r = 0; r < 4; ++r) {
        int row = j * 128 + 16 * wv + quad * 4 + r;
        bias4[j][r] = bih[row] + bhh[row];
      }

    int haveh0 = 0, haveh1 = 0, haveh2 = 0, haveh3 = 0;
    int havec0 = 0, havec1 = 0, havec2 = 0, havec3 = 0;
    const int tt = tid >> 4, bb = tid & 15;  // staging: 1 thread per (step,row)
    const int swk = bb & 7;                  // write-side swizzle key
    for (int k = 0; k < NCHUNK_; ++k) {
      WAITP(fhp[0], k + 1, haveh0);
      WAITP(fhp[1], k + 1, haveh1);
      WAITP(fhp[2], k + 1, haveh2);
      WAITP(fhp[3], k + 1, haveh3);
      if (k >= XGRING_) {
        WAITP(fcp[0], k - (XGRING_ - 1), havec0);
        WAITP(fcp[1], k - (XGRING_ - 1), havec1);
        WAITP(fcp[2], k - (XGRING_ - 1), havec2);
        WAITP(fcp[3], k - (XGRING_ - 1), havec3);
      }
      // stage h chunk [32][16][128] -> LDS, row-swizzled
      {
        const uint4* gp = (const uint4*)(region +
            ((size_t)(bg * 16 + bb) * T_ + (size_t)(CHUNK_ * k + tt)) * H_);
        uint4* lp = (uint4*)&smem[(tt * 16 + bb) * HS_];
#pragma unroll
        for (int i = 0; i < 16; ++i) lp[i ^ swk] = gp[i];
      }
      __syncthreads();
      const int slot = k % XGRING_;
      for (int t = 0; t < CHUNK_; ++t) {
        f16x8 hi4[4];
#pragma unroll
        for (int kc = 0; kc < 4; ++kc)
          hi4[kc] = *(const f16x8*)&smem[(t * 16 + n16) * HS_ +
                                         ((kc * 32 + quad * 8) ^ (b8 << 3))];
        float* xp = xgo + (size_t)(slot * CHUNK_ + t) * 8192 + quad * 64 + n16 * 4;
#pragma unroll
        for (int j = 0; j < 4; ++j) {
          f32x4 a = bias4[j];
#pragma unroll
          for (int kc = 0; kc < 4; ++kc)
            a = MFMA16(wih[j][kc], hi4[kc], a);
          *(f32x4*)(xp + (size_t)(8 * j + wv) * 256) = a;
        }
      }
      __syncthreads();  // drains stores + protects LDS reuse
      if (tid == 0)
        __hip_atomic_store(fx_out, (unsigned int)(k + 1),
                           __ATOMIC_RELEASE, __HIP_MEMORY_SCOPE_AGENT);
    }
    return;
  }

  // ========================= Recurrence role =============================
  const int layer = bid >> 5;
  const int sl    = bid & 31;          // batch-4 slice
  const int bcol  = n16 & 3;           // batch column (mirror-4)
  const int rr    = n16 >> 2;          // which acc element this lane owns
  const int batch = sl * 4 + bcol;
  const float* Whh = (layer == 0) ? Whh0 : ((layer == 1) ? Whh1 : Whh2);

  unsigned short* hstate = smem;                 // [2][4][HS_]
  unsigned short* xb = smem + 2 * 4 * HS_;       // [8][4][8] (layer 0 only)

  f16x8 whh[4][4];
#pragma unroll
  for (int j = 0; j < 4; ++j)
#pragma unroll
    for (int kc = 0; kc < 4; ++kc)
      whh[j][kc] = load_w8(Whh + (size_t)(j * 128 + 16 * wv + n16) * H_ + kc * 32 + quad * 8);

  for (int i = tid; i < (2 * 4 * HS_) / 2; i += 512) ((unsigned int*)smem)[i] = 0u;

  float cc_ = 0.f;                     // single cell value per lane
  unsigned short dh16[GRP_];
  const bool r2 = (rr & 2) != 0, r1 = (rr & 1) != 0;
  const int hcol = 16 * wv + 4 * quad + rr;         // h index this lane owns
  const int wswz = (((hcol >> 3) ^ bcol) << 3) | (hcol & 7);  // swizzled idx
  unsigned int* fh_out = (layer < 2) ? &flags[(layer * 32 + sl) * FLAG_STRIDE_] : nullptr;

  // g4 = acc[rr] via 3 cndmask
#define SEL3(a_) (r1 ? (r2 ? (a_)[3] : (a_)[1]) : (r2 ? (a_)[2] : (a_)[0]))

  if (layer == 0) {
    // ------------------------- layer 0 ---------------------------------
    f32x4 bias4[4];
#pragma unroll
    for (int j = 0; j < 4; ++j)
#pragma unroll
      for (int r = 0; r < 4; ++r) {
        int row = j * 128 + 16 * wv + quad * 4 + r;
        bias4[j][r] = bih0[row] + bhh0[row];
      }
    f16x8 wx[4];
#pragma unroll
    for (int j = 0; j < 4; ++j)
#pragma unroll
      for (int i = 0; i < 8; ++i) wx[j][i] = (_Float16)0.f;
    if (quad == 0) {
#pragma unroll
      for (int j = 0; j < 4; ++j) {
        const float* p = Wih0 + (size_t)(j * 128 + 16 * wv + n16) * IN_;
#pragma unroll
        for (int i = 0; i < IN_; ++i) wx[j][i] = (_Float16)p[i];
      }
    }
    const int sn_x = tid & 3, st_x = tid >> 2;  // staging map (tid<32)
    float xraw[6];
    __syncthreads();   // zeros visible
    if (tid < 32) {
      const float* xp = x + ((size_t)(sl * 4 + sn_x) * T_ + st_x) * IN_;
#pragma unroll
      for (int i = 0; i < IN_; ++i) xraw[i] = xp[i];
      uint4 xr4;
      xr4.x = pack2(xraw[0], xraw[1]); xr4.y = pack2(xraw[2], xraw[3]);
      xr4.z = pack2(xraw[4], xraw[5]); xr4.w = 0u;
      *(uint4*)&xb[(st_x * 4 + sn_x) * 8] = xr4;
    }
    __syncthreads();

    for (int g = 0; g < NGRP_; ++g) {
      if (tid < 32 && g + 1 < NGRP_) {
        const float* xp = x + ((size_t)(sl * 4 + sn_x) * T_ + (8 * (g + 1) + st_x)) * IN_;
#pragma unroll
        for (int i = 0; i < IN_; ++i) xraw[i] = xp[i];   // drains at pack
      }
#pragma unroll
      for (int s = 0; s < GRP_; ++s) {
        const int rp = s & 1, wp = rp ^ 1;
        f16x8 hs[4];
#pragma unroll
        for (int kc = 0; kc < 4; ++kc)
          hs[kc] = *(const f16x8*)&hstate[(rp * 4 + bcol) * HS_ +
                                          ((kc * 32 + quad * 8) ^ (bcol << 3))];
        f16x8 xi;
#pragma unroll
        for (int i = 0; i < 8; ++i) xi[i] = (_Float16)0.f;
        if (quad == 0) xi = *(const f16x8*)&xb[(s * 4 + bcol) * 8];
        // --- pair 1: gates i,f ---
        f32x4 a0 = MFMA16(wx[0], xi, bias4[0]);
        f32x4 a1 = MFMA16(wx[1], xi, bias4[1]);
#pragma unroll
        for (int kc = 0; kc < 4; ++kc) {
          a0 = MFMA16(whh[0][kc], hs[kc], a0);
          a1 = MFMA16(whh[1][kc], hs[kc], a1);
        }
        float gi = SEL3(a0), gf = SEL3(a1);
        float ei = __expf(-gi), ef = __expf(-gf);   // trans overlaps pair 2
        // --- pair 2: gates g,o ---
        f32x4 a2 = MFMA16(wx[2], xi, bias4[2]);
        f32x4 a3 = MFMA16(wx[3], xi, bias4[3]);
#pragma unroll
        for (int kc = 0; kc < 4; ++kc) {
          a2 = MFMA16(whh[2][kc], hs[kc], a2);
          a3 = MFMA16(whh[3][kc], hs[kc], a3);
        }
        float gg = SEL3(a2), go = SEL3(a3);
        float i_ = __builtin_amdgcn_rcpf(1.0f + ei);
        float f_ = __builtin_amdgcn_rcpf(1.0f + ef);
        float t_ = tanhf_(gg), o_ = sigf_(go);
        cc_ = f_ * cc_ + i_ * t_;
        float h_ = o_ * tanhf_(cc_);
        unsigned short uh = f2h_u(h_);
        dh16[s] = uh;
        hstate[(wp * 4 + bcol) * HS_ + wswz] = uh;
        BARRIER_LGKM();
      }
      // deferred h stores (in flight until chunk publish) + x staging
#pragma unroll
      for (int s = 0; s < GRP_; ++s)
        region[((size_t)batch * T_ + (8 * g + s)) * H_ + hcol] = dh16[s];
      if (tid < 32 && g + 1 < NGRP_) {
        uint4 xr4;
        xr4.x = pack2(xraw[0], xraw[1]); xr4.y = pack2(xraw[2], xraw[3]);
        xr4.z = pack2(xraw[4], xraw[5]); xr4.w = 0u;
        *(uint4*)&xb[(st_x * 4 + sn_x) * 8] = xr4;
      }
      BARRIER_LGKM();  // publishes xb; region stores stay in flight
      if ((g & 3) == 3) {
        PUBLISH_FENCE();  // ALL waves drain region stores before signal
        if (tid == 0)
          __hip_atomic_store(fh_out, (unsigned int)((g >> 2) + 1),
                             __ATOMIC_RELEASE, __HIP_MEMORY_SCOPE_AGENT);
      }
    }
  } else {
    // ----------------------- layers 1 and 2 ----------------------------
    const int bg = sl >> 2;
    const float* xgi = xg + (size_t)((layer - 1) * 8 + bg) * (XGRING_ * (size_t)XGSLOT_);
    const int lane_off = quad * 64 + ((sl & 3) * 4 + bcol) * 4 + wv * 256;
    f32x4 xr[2][4];
    // cbase = slot base for the current chunk; per-load offset is (t&31)*8192.
    auto load_xg = [&](const float* cb, int tin, int buf) {
      const float* p = cb + (size_t)tin * 8192 + lane_off;
      xr[buf][0] = *(const f32x4*)(p);
      xr[buf][1] = *(const f32x4*)(p + 2048);
      xr[buf][2] = *(const f32x4*)(p + 4096);
      xr[buf][3] = *(const f32x4*)(p + 6144);
    };
    unsigned int* fx_in  = &flags[(128 + (layer - 1) * 8 + bg) * FLAG_STRIDE_];
    unsigned int* fc_out = &flags[(144 + (layer - 1) * 64 + sl) * FLAG_STRIDE_];
    int have_x = 0;
    const float* cbase = xgi;
    __syncthreads();  // hstate zeros visible

    for (int g = 0; g < NGRP_; ++g) {
      if ((g & 3) == 0) {
        int c = g >> 2;
        WAITP(fx_in, c + 1, have_x);
        cbase = xgi + (size_t)((c % XGRING_) * CHUNK_) * 8192;
        load_xg(cbase, 0, 0);
        load_xg(cbase, 1, 1);
      }
#pragma unroll
      for (int s = 0; s < GRP_; ++s) {
        const int t = 8 * g + s;
        const int rp = s & 1, wp = rp ^ 1;
        f16x8 hs[4];
#pragma unroll
        for (int kc = 0; kc < 4; ++kc)
          hs[kc] = *(const f16x8*)&hstate[(rp * 4 + bcol) * HS_ +
                                          ((kc * 32 + quad * 8) ^ (bcol << 3))];
        // --- pair 1: gates i,f ---
        f32x4 a0 = xr[s & 1][0];
        f32x4 a1 = xr[s & 1][1];
#pragma unroll
        for (int kc = 0; kc < 4; ++kc) {
          a0 = MFMA16(whh[0][kc], hs[kc], a0);
          a1 = MFMA16(whh[1][kc], hs[kc], a1);
        }
        float gi = SEL3(a0), gf = SEL3(a1);
        float ei = __expf(-gi), ef = __expf(-gf);   // trans overlaps pair 2
        // --- pair 2: gates g,o ---
        f32x4 a2 = xr[s & 1][2];
        f32x4 a3 = xr[s & 1][3];
#pragma unroll
        for (int kc = 0; kc < 4; ++kc) {
          a2 = MFMA16(whh[2][kc], hs[kc], a2);
          a3 = MFMA16(whh[3][kc], hs[kc], a3);
        }
        // next-step xg prefetch (xr[s&1] fully consumed above)
        if (!(((g & 3) == 3) && s >= 6)) load_xg(cbase, (t + 2) & 31, s & 1);
        float gg = SEL3(a2), go = SEL3(a3);
        float i_ = __builtin_amdgcn_rcpf(1.0f + ei);
        float f_ = __builtin_amdgcn_rcpf(1.0f + ef);
        float t_ = tanhf_(gg), o_ = sigf_(go);
        cc_ = f_ * cc_ + i_ * t_;
        float h_ = o_ * tanhf_(cc_);
        unsigned short uh = f2h_u(h_);
        dh16[s] = uh;
        hstate[(wp * 4 + bcol) * HS_ + wswz] = uh;
        BARRIER_LGKM();
      }
      if (layer == 1) {
#pragma unroll
        for (int s = 0; s < GRP_; ++s)
          region[((size_t)batch * T_ + (8 * g + s)) * H_ + hcol] = dh16[s];
      }
      if ((g & 3) == 3) {
        PUBLISH_FENCE();  // drains region stores + this chunk's xg loads
        if (tid == 0) {
          unsigned int cdone = (unsigned int)((g >> 2) + 1);
          if (layer == 1)
            __hip_atomic_store(fh_out, cdone, __ATOMIC_RELEASE, __HIP_MEMORY_SCOPE_AGENT);
          __hip_atomic_store(fc_out, cdone, __ATOMIC_RELEASE, __HIP_MEMORY_SCOPE_AGENT);
        }
      }
    }
    if (layer == 2)
      ((unsigned short*)state_h)[(size_t)batch * 128 + hcol] = dh16[GRP_ - 1];
  }
#undef WAITP
#undef SEL3
}

// ---------------------------------------------------------------------------
__global__ void head_kernel(const unsigned int* __restrict__ state_h,
                            const float* __restrict__ Wout,
                            const float* __restrict__ bout,
                            float* __restrict__ out)
{
  int b = threadIdx.x;  // 128 threads, 1 block
  float s = bout[0];
  for (int j = 0; j < 64; ++j) {
    unsigned int p = state_h[b * 64 + j];
    union { unsigned short u; _Float16 h; } lo, hi;
    lo.u = (unsigned short)(p & 0xffffu);
    hi.u = (unsigned short)(p >> 16);
    s += (float)lo.h * Wout[2 * j] + (float)hi.h * Wout[2 * j + 1];
  }
  out[b] = s;
}

// ---------------------------------------------------------------------------
extern "C" void kernel_launch(void* const* d_in, const int* in_sizes, int n_in,
                              void* d_out, int out_size, void* d_ws, size_t ws_size,
                              hipStream_t stream)
{
  const float* x = (const float*)d_in[0];
  const float* Wih[3] = {(const float*)d_in[1], (const float*)d_in[5], (const float*)d_in[9]};
  const float* Whh[3] = {(const float*)d_in[2], (const float*)d_in[6], (const float*)d_in[10]};
  const float* bih[3] = {(const float*)d_in[3], (const float*)d_in[7], (const float*)d_in[11]};
  const float* bhh[3] = {(const float*)d_in[4], (const float*)d_in[8], (const float*)d_in[12]};
  const float* Wout = (const float*)d_in[13];
  const float* bout = (const float*)d_in[14];
  float* out = (float*)d_out;

  char* ws = (char*)d_ws;
  size_t off = 0;
  unsigned short* region = (unsigned short*)(ws + off); off += (size_t)B_ * T_ * H_ * 2;   // 64 MiB
  float* xg = (float*)(ws + off);                       off += (size_t)16 * XGRING_ * XGSLOT_ * 4;  // 48 MiB
  unsigned int* state_h  = (unsigned int*)(ws + off);   off += (size_t)B_ * 64 * 4;
  off = (off + 255) & ~(size_t)255;
  unsigned int* flags    = (unsigned int*)(ws + off);   off += NFLAGS_ * FLAG_STRIDE_ * 4;

  init_flags<<<68, 256, 0, stream>>>(flags);
  lstm_pipe<<<112, 512, 0, stream>>>(x,
      Wih[0], Whh[0], bih[0], bhh[0],
      Wih[1], Whh[1], bih[1], bhh[1],
      Wih[2], Whh[2], bih[2], bhh[2],
      region, xg, state_h, flags);
  head_kernel<<<1, 128, 0, stream>>>(state_h, Wout, bout, out);
}